// Round 15
// baseline (338.338 us; speedup 1.0000x reference)
//
#include <hip/hip_runtime.h>

// Input (16,32,382,255) f32 ; output tensor (16,32,765,765) f32
// + u_min/u_max/v_min/v_max (16 each) as floats after the tensor.
//
// out[b,c,u,v] = in[b,c,u-ulo,v-vlo] when (u-ulo) in [0,382), (v-vlo) in
// [0,255), else 0.  ulo = 255-(q-r/2) in [1,382]; vlo = 382-r in [128,382].
//
// R15: no hipMemset — minimal-traffic split (1.40 GB total):
//   zero_fill : zeros the 383 non-band rows/plane (2 contiguous runs/plane,
//               pure aligned nt-f4 stores, no loads)            0.60 GB W
//   band_rows : writes band rows FULLY (span copy + zero sides) —
//               contiguous 1.17 MB store stream per plane       0.60 GB W + 0.20 GB R
namespace {
constexpr int kH = 382;               // input rows
constexpr int kW = 255;               // input cols
constexpr int kS = 765;               // output edge
constexpr int kPlaneIn  = kH * kW;    // 97410
constexpr int kPlaneOut = kS * kS;    // 585225
constexpr int kNPlanes  = 512;        // 16*32
constexpr int kZeroSlices = 8;
constexpr int kWavesPerPlane = 16;
constexpr int kRowsPerWave   = 24;    // 16*24 = 384 >= 382
constexpr int kBandBlocks = kNPlanes * kWavesPerPlane / 4;   // 2048
constexpr unsigned long long kOutElems =
    (unsigned long long)kNPlanes * (unsigned long long)kPlaneOut;  // 299,635,200
typedef float floatv4 __attribute__((ext_vector_type(4)));
}

__global__ __launch_bounds__(256) void zero_fill_kernel(
    const int* __restrict__ off, float* __restrict__ out)
{
    const int run   = (int)blockIdx.x;       // 0..1023 : plane*2 + which
    const int p     = run >> 1;
    const int which = run & 1;
    const int b     = p >> 5;

    const int q   = off[2 * b];
    const int r   = off[2 * b + 1];
    const int ulo = 255 - (q - (r >> 1));    // band first row, in [1,382]

    unsigned start; int ndw;
    if (which == 0) {                        // prefix rows [0, ulo)
        start = (unsigned)p * (unsigned)kPlaneOut;
        ndw   = ulo * kS;
    } else {                                 // suffix rows [ulo+382, 765)
        start = (unsigned)p * (unsigned)kPlaneOut + (unsigned)(ulo + kH) * (unsigned)kS;
        ndw   = (383 - ulo) * kS;
    }
    const int pad  = (int)((0u - start) & 3u);
    const int nvec = (ndw - pad) >> 2;
    const int tail = ndw - pad - 4 * nvec;

    const floatv4 z4 = {0.f, 0.f, 0.f, 0.f};
    for (int i = (int)(blockIdx.y * 256u + threadIdx.x); i < nvec;
         i += 256 * kZeroSlices) {
        __builtin_nontemporal_store(
            z4, reinterpret_cast<floatv4*>(out + start + pad + 4 * i));
    }
    if (blockIdx.y == 0) {
        const int t = (int)threadIdx.x;
        if (t < pad)  __builtin_nontemporal_store(0.f, out + start + t);
        if (t < tail) __builtin_nontemporal_store(0.f, out + start + pad + 4 * nvec + t);
    }
}

__global__ __launch_bounds__(256) void band_rows_kernel(
    const float* __restrict__ in, const int* __restrict__ off,
    float* __restrict__ out)
{
    if (blockIdx.x == (unsigned)kBandBlocks) {
        // ---- extras: u_min/u_max/v_min/v_max as floats after the tensor ----
        int i = (int)threadIdx.x;
        if (i < 64) {
            int b = i & 15;
            int which = i >> 4;
            int q = off[2 * b];
            int r = off[2 * b + 1];
            int u_min = 255 - (q - (r >> 1));
            int v_min = 382 - r;
            int val = (which == 0) ? u_min
                    : (which == 1) ? (u_min + kH)
                    : (which == 2) ? v_min
                                   : (v_min + kW);
            out[kOutElems + (unsigned)i] = (float)val;
        }
        return;
    }

    const int lane = (int)threadIdx.x & 63;
    const int gw   = (int)(blockIdx.x * 4u + ((unsigned)threadIdx.x >> 6));
    const int p    = gw >> 4;          // plane 0..511
    const int sub  = gw & 15;          // row-block within plane
    const int b    = p >> 5;

    const int q   = off[2 * b];
    const int r   = off[2 * b + 1];
    const int ulo = 255 - (q - (r >> 1));   // band first row
    const int vlo = 382 - r;                // span start col, in [128,382]

    const float* __restrict__ inplane = in + (size_t)p * (size_t)kPlaneIn;
    const unsigned outband = (unsigned)p * (unsigned)kPlaneOut
                           + (unsigned)ulo * (unsigned)kS;   // full-row band base

    const int h0 = sub * kRowsPerWave;
    const int h1 = (h0 + kRowsPerWave < kH) ? h0 + kRowsPerWave : kH;

    for (int h = h0; h < h1; ++h) {
        const float* __restrict__ inrow = inplane + (size_t)h * (size_t)kW;
        const unsigned S = outband + (unsigned)h * (unsigned)kS;  // row base (765 dw)

        const int pad  = (int)((0u - S) & 3u);
        const int nvec = (kS - pad) >> 2;        // 190 or 191
        const int tail = kS - pad - 4 * nvec;    // 0..3

        // head (d<=2 < vlo) and tail (d>=762 > vhi<=637) are always zero
        if (lane < pad)  __builtin_nontemporal_store(0.f, out + S + lane);
        if (lane < tail) __builtin_nontemporal_store(0.f, out + S + pad + 4 * nvec + lane);

#pragma unroll
        for (int j = 0; j < 3; ++j) {
            const int fi = lane + 64 * j;
            if (fi < nvec) {
                const int d   = pad + 4 * fi;
                const int rel = d - vlo;          // input col of component 0
                floatv4 v;
                if (rel >= 0 && rel + 3 < kW) {            // fully inside span
                    __builtin_memcpy(&v, inrow + rel, 16);
                } else if (rel + 3 < 0 || rel >= kW) {     // fully outside
                    v = (floatv4){0.f, 0.f, 0.f, 0.f};
                } else {                                   // straddle (2/row)
                    v.x = ((unsigned)(rel    ) < (unsigned)kW) ? inrow[rel]     : 0.f;
                    v.y = ((unsigned)(rel + 1) < (unsigned)kW) ? inrow[rel + 1] : 0.f;
                    v.z = ((unsigned)(rel + 2) < (unsigned)kW) ? inrow[rel + 2] : 0.f;
                    v.w = ((unsigned)(rel + 3) < (unsigned)kW) ? inrow[rel + 3] : 0.f;
                }
                __builtin_nontemporal_store(
                    v, reinterpret_cast<floatv4*>(out + S + d));
            }
        }
    }
}

extern "C" void kernel_launch(void* const* d_in, const int* in_sizes, int n_in,
                              void* d_out, int out_size, void* d_ws, size_t ws_size,
                              hipStream_t stream) {
    const float* in  = (const float*)d_in[0];
    const int*   off = (const int*)d_in[1];
    float*       out = (float*)d_out;

    // Phase 1: zero the non-band rows (pure stores, 0.60 GB).
    zero_fill_kernel<<<dim3(kNPlanes * 2, kZeroSlices), dim3(256), 0, stream>>>(off, out);
    // Phase 2: write band rows fully (contiguous stores) + extras block.
    band_rows_kernel<<<dim3(kBandBlocks + 1), dim3(256), 0, stream>>>(in, off, out);
}

// Round 16
// 313.212 us; speedup vs baseline: 1.0802x; 1.0802x over previous
//
#include <hip/hip_runtime.h>

// Input (16,32,382,255) f32 ; output tensor (16,32,765,765) f32
// + u_min/u_max/v_min/v_max (16 each) as floats after the tensor.
//
// out[b,c,u,v] = in[b,c,u-ulo,v-vlo] when (u-ulo) in [0,382), (v-vlo) in
// [0,255), else 0.  ulo = 255-(q-r/2) in [1,382]; vlo = 382-r in [128,382]
// -> copy band always fully interior.
//
// Final structure (best of 6 measured structures, 312.9 us):
//   hipMemsetAsync zeros the tensor via rocclr fillBufferAligned (6.5 TB/s
//   measured; every hand-rolled fill capped at ~3.5 TB/s, incl. a pure-store
//   contiguous no-load kernel) + band-copy kernel rewrites the 0.42 GB band
//   (contiguous per-wave reads, aligned nt float4 stores, 2-row pipeline).
namespace {
constexpr int kH = 382;               // input rows
constexpr int kW = 255;               // input cols
constexpr int kS = 765;               // output edge
constexpr int kPlaneIn  = kH * kW;    // 97410
constexpr int kPlaneOut = kS * kS;    // 585225
constexpr int kNPlanes  = 512;        // 16*32
constexpr int kWavesPerPlane = 16;
constexpr int kRowsPerWave   = 24;    // waves 0..14: 24 rows; wave 15: 22 (even)
constexpr int kCopyBlocks = kNPlanes * kWavesPerPlane / 4;   // 2048
constexpr unsigned long long kOutElems =
    (unsigned long long)kNPlanes * (unsigned long long)kPlaneOut;  // 299,635,200
typedef float floatv4 __attribute__((ext_vector_type(4)));
}

__global__ __launch_bounds__(256) void band_copy_kernel(
    const float* __restrict__ in, const int* __restrict__ off,
    float* __restrict__ out)
{
    if (blockIdx.x == (unsigned)kCopyBlocks) {
        // ---- extras: u_min/u_max/v_min/v_max as floats after the tensor ----
        int i = (int)threadIdx.x;     // 64 active
        if (i < 64) {
            int b = i & 15;
            int which = i >> 4;       // 0:u_min 1:u_max 2:v_min 3:v_max
            int q = off[2 * b];
            int r = off[2 * b + 1];
            int u_min = 255 - (q - (r >> 1));
            int v_min = 382 - r;
            int val = (which == 0) ? u_min
                    : (which == 1) ? (u_min + kH)
                    : (which == 2) ? v_min
                                   : (v_min + kW);
            out[kOutElems + (unsigned)i] = (float)val;
        }
        return;
    }

    const int lane = (int)threadIdx.x & 63;
    const int gw   = (int)(blockIdx.x * 4u + ((unsigned)threadIdx.x >> 6));
    const int p    = gw >> 4;          // plane 0..511 (b*32 + c)
    const int sub  = gw & 15;          // wave's row-block within the plane
    const int b    = p >> 5;

    const int q   = off[2 * b];
    const int r   = off[2 * b + 1];
    const int ulo = 255 - (q - (r >> 1));   // first band row, in [1,382]
    const int vlo = 382 - r;                // first valid col, in [128,382]

    const unsigned inplane = (unsigned)p * (unsigned)kPlaneIn;
    const unsigned outband = (unsigned)p * (unsigned)kPlaneOut
                           + (unsigned)ulo * (unsigned)kS + (unsigned)vlo;

    const int h0 = sub * kRowsPerWave;                       // contiguous rows
    const int h1 = (h0 + kRowsPerWave < kH) ? h0 + kRowsPerWave : kH;

    for (int h = h0; h < h1; h += 2) {
        // ---- row pair: issue all loads, then all stores ----
        const unsigned inA = inplane + (unsigned)h * (unsigned)kW;
        const unsigned inB = inA + (unsigned)kW;
        const unsigned SA  = outband + (unsigned)h * (unsigned)kS;
        const unsigned SB  = SA + (unsigned)kS;

        const int padA  = (int)((0u - SA) & 3u);
        const int padB  = (int)((0u - SB) & 3u);
        const int nvecA = (kW - padA) >> 2;
        const int nvecB = (kW - padB) >> 2;
        const int tailA = kW - padA - 4 * nvecA;
        const int tailB = kW - padB - 4 * nvecB;

        const bool vA = (lane < nvecA), vB = (lane < nvecB);
        const int  dA = padA + 4 * lane, dB = padB + 4 * lane;

        floatv4 a, c;
        if (vA) __builtin_memcpy(&a, in + inA + dA, 16);
        if (vB) __builtin_memcpy(&c, in + inB + dB, 16);

        float pA = 0.f, pB = 0.f, tA = 0.f, tB = 0.f;
        const int dtA = padA + 4 * nvecA + lane;
        const int dtB = padB + 4 * nvecB + lane;
        if (lane < padA)  pA = in[inA + lane];
        if (lane < padB)  pB = in[inB + lane];
        if (lane < tailA) tA = in[inA + dtA];
        if (lane < tailB) tB = in[inB + dtB];

        if (vA) __builtin_nontemporal_store(a, reinterpret_cast<floatv4*>(out + SA + dA));
        if (vB) __builtin_nontemporal_store(c, reinterpret_cast<floatv4*>(out + SB + dB));
        if (lane < padA)  __builtin_nontemporal_store(pA, out + SA + lane);
        if (lane < padB)  __builtin_nontemporal_store(pB, out + SB + lane);
        if (lane < tailA) __builtin_nontemporal_store(tA, out + SA + dtA);
        if (lane < tailB) __builtin_nontemporal_store(tB, out + SB + dtB);
    }
}

extern "C" void kernel_launch(void* const* d_in, const int* in_sizes, int n_in,
                              void* d_out, int out_size, void* d_ws, size_t ws_size,
                              hipStream_t stream) {
    const float* in  = (const float*)d_in[0];
    const int*   off = (const int*)d_in[1];
    float*       out = (float*)d_out;

    // Bulk zero via rocclr fill kernel (6.5 TB/s measured on this buffer).
    hipMemsetAsync(out, 0, kOutElems * sizeof(float), stream);
    // Rewrite the interior copy band (0.62 GB traffic) + extras block.
    band_copy_kernel<<<dim3(kCopyBlocks + 1), dim3(256), 0, stream>>>(in, off, out);
}